// Round 4
// baseline (296.499 us; speedup 1.0000x reference)
//
#include <hip/hip_runtime.h>
#include <cstdint>
#include <math.h>

// GeometricAttention: B=4,H=8,N=2048, D = 8*16 (mv, IPF on q) + 16 (s) = 144
// R4: fragment-ordered K/V^T packing (all main-kernel ds_read_b128 are wave-contiguous
// 1024B blocks -> conflict-free), M=32 rows/wave (2 row-groups share K/V frag reads),
// 256-thr blocks, LDS 38.9KB (sP aliased in sK) -> 3 blocks/CU.

#define BH    32
#define N_    2048
#define DMV   128
#define DS    16
#define D_    144
#define BM    128          // Q rows per block (4 waves x 32 rows)
#define BN    64           // KV rows per iteration
#define NKIT  (N_ / BN)    // 32
#define PSTR  72           // sP row stride (elems); read classes partition banks
#define KTILE_E  10240     // K tile: 20 frags x 512 elems (k 0..159, zero-padded >143)
#define VTILE_E  9216      // V^T tile: 18 frags x 512 elems
#define KP_BYTES ((size_t)BH * NKIT * KTILE_E * 2)   // 20.97 MB
#define QSCALE 0.12022458674074693f  // (1/12) * log2(e)

typedef __bf16 bf16_8 __attribute__((ext_vector_type(8)));
typedef float  f32x4  __attribute__((ext_vector_type(4)));

#define GLOAD_LDS16(g, l)                                                     \
  __builtin_amdgcn_global_load_lds(                                           \
      (const __attribute__((address_space(1))) void*)(g),                     \
      (__attribute__((address_space(3))) void*)(l), 16, 0, 0)

__device__ __forceinline__ f32x4 mfma16(bf16_8 a, bf16_8 b, f32x4 c) {
  return __builtin_amdgcn_mfma_f32_16x16x32_bf16(a, b, c, 0, 0, 0);
}

// ---------------- pre-pass 1: K -> fragment-ordered bf16 tiles -----------------------
// tile (bh,it): chunk c = (nt*5+ks)*64 + quad*16 + l15 holds K[nt*16+l15][ks*32+quad*8 ..+7]
__global__ __launch_bounds__(256)
void pack_k(const float* __restrict__ kmv, const float* __restrict__ ks_,
            __bf16* __restrict__ kp) {
  const int tile = blockIdx.x;                    // bh*32 + it
  const int t = threadIdx.x;
  __bf16* dst = kp + (size_t)tile * KTILE_E;
#pragma unroll
  for (int u = 0; u < 5; ++u) {
    int c = t + 256 * u;                          // < 1280
    int f = c >> 6, r = c & 63;
    int nt = f / 5, ks = f - nt * 5;
    int quad = r >> 4, l15 = r & 15;
    int n = tile * 64 + nt * 16 + l15;            // global KV row (within bh*N flat)
    int k = ks * 32 + quad * 8;
    bf16_8 o;
    if (k < DMV) {
      const f32x4* p = (const f32x4*)(kmv + (size_t)n * DMV + k);
      f32x4 a = p[0], b = p[1];
#pragma unroll
      for (int j = 0; j < 8; ++j) o[j] = (__bf16)((j < 4) ? a[j] : b[j - 4]);
    } else if (k < D_) {
      const f32x4* p = (const f32x4*)(ks_ + (size_t)n * DS + (k - DMV));
      f32x4 a = p[0], b = p[1];
#pragma unroll
      for (int j = 0; j < 8; ++j) o[j] = (__bf16)((j < 4) ? a[j] : b[j - 4]);
    } else {
#pragma unroll
      for (int j = 0; j < 8; ++j) o[j] = (__bf16)0.0f;
    }
    *(bf16_8*)(dst + (size_t)c * 8) = o;
  }
}

// ---------------- pre-pass 2: V^T -> fragment-ordered bf16 tiles ---------------------
// chunk c = (n9*2+ks)*64 + quad*16 + l15 holds V[ks*32+quad*8+j][n9*16+l15], j=0..7
#define TSTR 156
__global__ __launch_bounds__(256)
void pack_vt(const float* __restrict__ vmv, const float* __restrict__ vs,
             __bf16* __restrict__ vt) {
  __shared__ __bf16 sT[64 * TSTR];
  const int tile = blockIdx.x;                    // bh*32 + it
  const int t = threadIdx.x;
  {                                               // stage rows -> LDS bf16
    const int n = t >> 2, c4 = t & 3;
    const float* mv = vmv + (size_t)(tile * 64 + n) * DMV;
    const float* s  = vs  + (size_t)(tile * 64 + n) * DS;
    __bf16* row = &sT[n * TSTR];
    if (c4 < 3) {
#pragma unroll
      for (int i = 0; i < 9; ++i) {
        f32x4 x = *(const f32x4*)(mv + c4 * 36 + 4 * i);
#pragma unroll
        for (int j = 0; j < 4; ++j) row[c4 * 36 + 4 * i + j] = (__bf16)x[j];
      }
    } else {
#pragma unroll
      for (int i = 0; i < 5; ++i) {
        f32x4 x = *(const f32x4*)(mv + 108 + 4 * i);
#pragma unroll
        for (int j = 0; j < 4; ++j) row[108 + 4 * i + j] = (__bf16)x[j];
      }
#pragma unroll
      for (int i = 0; i < 4; ++i) {
        f32x4 x = *(const f32x4*)(s + 4 * i);
#pragma unroll
        for (int j = 0; j < 4; ++j) row[128 + 4 * i + j] = (__bf16)x[j];
      }
    }
  }
  __syncthreads();
  __bf16* dst = vt + (size_t)tile * VTILE_E;
  for (int c = t; c < 1152; c += 256) {
    int f = c >> 6, r = c & 63;
    int n9 = f >> 1, ks = f & 1;
    int quad = r >> 4, l15 = r & 15;
    int d = n9 * 16 + l15;
    int n0 = ks * 32 + quad * 8;
    bf16_8 o;
#pragma unroll
    for (int j = 0; j < 8; ++j) o[j] = sT[(n0 + j) * TSTR + d];
    *(bf16_8*)(dst + (size_t)c * 8) = o;
  }
}

// ---------------- Q fragment load: IPF sign + scale, fp32 -> bf16 --------------------
__device__ __forceinline__ bf16_8 load_q_frag(const float* qmv_row, const float* qs_row, int k0) {
  bf16_8 f;
  if (k0 < DMV) {
    const f32x4* p = (const f32x4*)(qmv_row + k0);
    f32x4 a = p[0], b = p[1];
    // IPF = [1,1,-1,-1,-1,-1,-1,-1, 1,1,1,1,1,1,-1,-1]; k0&8 selects which half.
    int hi = k0 & 8;
#pragma unroll
    for (int j = 0; j < 8; ++j) {
      float v = (j < 4) ? a[j] : b[j - 4];
      bool pos = hi ? (j < 6) : (j < 2);
      f[j] = (__bf16)(v * (pos ? QSCALE : -QSCALE));
    }
  } else if (k0 < D_) {
    const f32x4* p = (const f32x4*)(qs_row + (k0 - DMV));
    f32x4 a = p[0], b = p[1];
#pragma unroll
    for (int j = 0; j < 8; ++j) {
      float v = (j < 4) ? a[j] : b[j - 4];
      f[j] = (__bf16)(v * QSCALE);
    }
  } else {
#pragma unroll
    for (int j = 0; j < 8; ++j) f[j] = (__bf16)0.0f;
  }
  return f;
}

// ---------------- main flash kernel (256 thr, 4 waves x 32 Q-rows) -------------------
__global__ __launch_bounds__(256, 3)
void geo_attn_kernel(const float* __restrict__ q_mv, const float* __restrict__ q_s,
                     const __bf16* __restrict__ kp, const __bf16* __restrict__ vt,
                     float* __restrict__ out)
{
  __shared__ __bf16 sK[KTILE_E];      // 20480 B; sP (4x2304 elems) aliased inside
  __shared__ __bf16 sVT[VTILE_E];     // 18432 B

  const int tid  = threadIdx.x;
  const int w    = tid >> 6;        // wave 0..3
  const int lane = tid & 63;
  const int l15  = lane & 15;
  const int quad = lane >> 4;
  const int bh    = blockIdx.y;
  const int qbase = blockIdx.x * BM;
  const size_t bh_n = (size_t)bh * N_;

  __bf16* sPw = sK + w * (32 * PSTR);   // per-wave 32x72 P region (4608 B)

  // ---- Q fragments in registers: B-operand layout, lane l15 = Q row within 16
  bf16_8 qf[2][5];
#pragma unroll
  for (int rg = 0; rg < 2; ++rg) {
    int mrow = qbase + 32 * w + 16 * rg + l15;
    const float* qmv_row = q_mv + (bh_n + mrow) * DMV;
    const float* qs_row  = q_s  + (bh_n + mrow) * DS;
#pragma unroll
    for (int ks = 0; ks < 5; ++ks)
      qf[rg][ks] = load_q_frag(qmv_row, qs_row, ks * 32 + quad * 8);
  }

  f32x4 of[2][9];
#pragma unroll
  for (int rg = 0; rg < 2; ++rg)
#pragma unroll
    for (int n9 = 0; n9 < 9; ++n9)
#pragma unroll
      for (int r = 0; r < 4; ++r) of[rg][n9][r] = 0.0f;
  float m_i[2] = {-INFINITY, -INFINITY}, l_i[2] = {0.0f, 0.0f};

  const __bf16* kbase = kp + (size_t)bh * NKIT * KTILE_E;
  const __bf16* vbase = vt + (size_t)bh * NKIT * VTILE_E;

  for (int it = 0; it < NKIT; ++it) {
    // ======== stage K,V tiles via global->LDS DMA (contiguous 1024B chunks) ========
    {
      const __bf16* kt = kbase + (size_t)it * KTILE_E;
      const __bf16* vp = vbase + (size_t)it * VTILE_E;
      for (int i = w; i < 20; i += 4)
        GLOAD_LDS16(kt + i * 512 + lane * 8, &sK[i * 512 + lane * 8]);
      for (int i = w; i < 18; i += 4)
        GLOAD_LDS16(vp + i * 512 + lane * 8, &sVT[i * 512 + lane * 8]);
    }
    __syncthreads();   // vmcnt drained -> tiles resident

    // ======== S^T = K Q^T : frag reads are wave-contiguous 1024B blocks ========
    f32x4 sf[2][4];
#pragma unroll
    for (int rg = 0; rg < 2; ++rg)
#pragma unroll
      for (int nt = 0; nt < 4; ++nt)
#pragma unroll
        for (int r = 0; r < 4; ++r) sf[rg][nt][r] = 0.0f;
#pragma unroll
    for (int ks = 0; ks < 5; ++ks) {
#pragma unroll
      for (int nt = 0; nt < 4; ++nt) {
        bf16_8 kb = *(const bf16_8*)&sK[(nt * 5 + ks) * 512 + lane * 8];
        sf[0][nt] = mfma16(kb, qf[0][ks], sf[0][nt]);
        sf[1][nt] = mfma16(kb, qf[1][ks], sf[1][nt]);
      }
    }
    __syncthreads();   // all sK frag reads done before sP (alias) writes

    // ======== online softmax: row m = l15 per rg, 2-shuffle reductions ========
#pragma unroll
    for (int rg = 0; rg < 2; ++rg) {
      float mx = sf[rg][0][0];
#pragma unroll
      for (int nt = 0; nt < 4; ++nt)
#pragma unroll
        for (int r = 0; r < 4; ++r) mx = fmaxf(mx, sf[rg][nt][r]);
      mx = fmaxf(mx, __shfl_xor(mx, 16));
      mx = fmaxf(mx, __shfl_xor(mx, 32));
      float mnew = fmaxf(m_i[rg], mx);
      float al = __builtin_amdgcn_exp2f(m_i[rg] - mnew);
      m_i[rg] = mnew;
      float rs = 0.0f;
#pragma unroll
      for (int nt = 0; nt < 4; ++nt)
#pragma unroll
        for (int r = 0; r < 4; ++r) {
          float p = __builtin_amdgcn_exp2f(sf[rg][nt][r] - mnew);
          sf[rg][nt][r] = p;
          rs += p;
        }
      rs += __shfl_xor(rs, 16);
      rs += __shfl_xor(rs, 32);
      l_i[rg] = l_i[rg] * al + rs;

      // P write: row m = rg*16+l15, col n = nt*16+quad*4+r -> one b64 per nt
#pragma unroll
      for (int nt = 0; nt < 4; ++nt) {
        __bf16 pw[4];
#pragma unroll
        for (int r = 0; r < 4; ++r) pw[r] = (__bf16)sf[rg][nt][r];
        *(uint64_t*)&sPw[(rg * 16 + l15) * PSTR + nt * 16 + quad * 4] = *(uint64_t*)pw;
      }

      // alpha to O-row indexing (row quad*4+r): srclane = quad*16 + quad*4 + r
      float alr[4];
#pragma unroll
      for (int r = 0; r < 4; ++r) alr[r] = __shfl(al, 20 * quad + r);
#pragma unroll
      for (int n9 = 0; n9 < 9; ++n9)
#pragma unroll
        for (int r = 0; r < 4; ++r) of[rg][n9][r] *= alr[r];
    }
    asm volatile("s_waitcnt lgkmcnt(0)" ::: "memory");  // sPw is wave-private

    // ======== O += P V (V frag reads wave-contiguous; sP reads bank-partitioned) ====
#pragma unroll
    for (int ks = 0; ks < 2; ++ks) {
      bf16_8 pa[2];
#pragma unroll
      for (int rg = 0; rg < 2; ++rg)
        pa[rg] = *(const bf16_8*)&sPw[(rg * 16 + l15) * PSTR + ks * 32 + quad * 8];
#pragma unroll
      for (int n9 = 0; n9 < 9; ++n9) {
        bf16_8 vb = *(const bf16_8*)&sVT[(n9 * 2 + ks) * 512 + lane * 8];
        of[0][n9] = mfma16(pa[0], vb, of[0][n9]);
        of[1][n9] = mfma16(pa[1], vb, of[1][n9]);
      }
    }
    __syncthreads();  // sVT/sP reads done before next iteration's staging
  }

  // ======== epilogue: O /= l (redistributed to O-rows), write fp32 ========
  float* out_mv = out;
  float* out_s  = out + (size_t)BH * N_ * DMV;
#pragma unroll
  for (int rg = 0; rg < 2; ++rg) {
    float linv[4];
#pragma unroll
    for (int r = 0; r < 4; ++r)
      linv[r] = __builtin_amdgcn_rcpf(__shfl(l_i[rg], 20 * quad + r));
#pragma unroll
    for (int n9 = 0; n9 < 9; ++n9) {
#pragma unroll
      for (int r = 0; r < 4; ++r) {
        int row = qbase + 32 * w + 16 * rg + quad * 4 + r;
        float val = of[rg][n9][r] * linv[r];
        if (n9 < 8) out_mv[(bh_n + row) * DMV + n9 * 16 + l15] = val;
        else        out_s [(bh_n + row) * DS + l15] = val;
      }
    }
  }
}

extern "C" void kernel_launch(void* const* d_in, const int* in_sizes, int n_in,
                              void* d_out, int out_size, void* d_ws, size_t ws_size,
                              hipStream_t stream) {
  (void)in_sizes; (void)n_in; (void)out_size; (void)ws_size;
  const float* q_mv = (const float*)d_in[0];
  const float* k_mv = (const float*)d_in[1];
  const float* v_mv = (const float*)d_in[2];
  const float* q_s  = (const float*)d_in[3];
  const float* k_s  = (const float*)d_in[4];
  const float* v_s  = (const float*)d_in[5];
  float* out = (float*)d_out;

  __bf16* kp = (__bf16*)d_ws;                              // 20,971,520 B
  __bf16* vt = (__bf16*)((char*)d_ws + KP_BYTES);          // 18,874,368 B

  pack_k<<<BH * NKIT, 256, 0, stream>>>(k_mv, k_s, kp);
  pack_vt<<<BH * NKIT, 256, 0, stream>>>(v_mv, v_s, vt);

  dim3 grid(N_ / BM, BH);
  geo_attn_kernel<<<grid, 256, 0, stream>>>(q_mv, q_s, kp, vt, out);
}